// Round 1
// baseline (3029.637 us; speedup 1.0000x reference)
//
#include <hip/hip_runtime.h>
#include <math.h>

#define BB   4
#define TT   1024
#define CC   768
#define HH   12
#define SS   64
#define FFD  3072
#define HIDD 2048
#define NTOK (BB*TT)          // 4096
#define EPSR 1e-6f
#define QB   32

// ---------------- global sum-of-squares (two-stage, deterministic) -------
__global__ void k_sumsq_partial(const float* __restrict__ x, float* __restrict__ part, int n4) {
    __shared__ float sm[256];
    float s = 0.f;
    int stride = gridDim.x * blockDim.x;
    for (int i = blockIdx.x * blockDim.x + threadIdx.x; i < n4; i += stride) {
        float4 v = ((const float4*)x)[i];
        s += v.x*v.x + v.y*v.y + v.z*v.z + v.w*v.w;
    }
    sm[threadIdx.x] = s;
    __syncthreads();
    for (int off = 128; off > 0; off >>= 1) {
        if (threadIdx.x < off) sm[threadIdx.x] += sm[threadIdx.x + off];
        __syncthreads();
    }
    if (threadIdx.x == 0) part[blockIdx.x] = sm[0];
}

__global__ void k_sumsq_final(const float* __restrict__ part, float* __restrict__ outscale,
                              int npart, float invn) {
    __shared__ float sm[256];
    float s = 0.f;
    for (int i = threadIdx.x; i < npart; i += 256) s += part[i];
    sm[threadIdx.x] = s;
    __syncthreads();
    for (int off = 128; off > 0; off >>= 1) {
        if (threadIdx.x < off) sm[threadIdx.x] += sm[threadIdx.x + off];
        __syncthreads();
    }
    if (threadIdx.x == 0) outscale[0] = 1.0f / sqrtf(EPSR + sm[0] * invn);
}

// ---------------- h = x * scale * gamma[c] -------------------------------
__global__ void k_scale_gamma(const float* __restrict__ x, const float* __restrict__ g,
                              const float* __restrict__ scale, float* __restrict__ h, int n4) {
    int i = blockIdx.x * blockDim.x + threadIdx.x;
    if (i >= n4) return;
    float sc = scale[0];
    float4 v = ((const float4*)x)[i];
    int c = (i * 4) % CC;
    float4 gg = *(const float4*)(g + c);
    float4 r;
    r.x = v.x * sc * gg.x; r.y = v.y * sc * gg.y;
    r.z = v.z * sc * gg.z; r.w = v.w * sc * gg.w;
    ((float4*)h)[i] = r;
}

// ---------------- repack Wq/Wk/Wv [H,C,S] -> [C, 3C] ----------------------
__global__ void k_repack(const float* __restrict__ W, float* __restrict__ wpk, int colofs) {
    int i = blockIdx.x * blockDim.x + threadIdx.x;  // over H*C*S
    if (i >= HH * CC * SS) return;
    int s = i % SS;
    int c = (i / SS) % CC;
    int h = i / (SS * CC);
    wpk[(size_t)c * (3 * CC) + colofs + h * SS + s] = W[i];
}

// ---------------- rope cos/sin table [T][32] ------------------------------
__global__ void k_rope_table(float* __restrict__ tab) {
    int i = blockIdx.x * blockDim.x + threadIdx.x;  // T*32
    if (i >= TT * 32) return;
    int t = i >> 5, j = i & 31;
    // theta_j = 10000^(-j/16) = exp(-j * ln(10000)/16)
    float th = expf(-(float)j * 0.5756462732485115f);
    float ang = (float)t * th;
    tab[2 * i]     = cosf(ang);
    tab[2 * i + 1] = sinf(ang);
}

// ---------------- apply rope in-place to q,k parts of qkv -----------------
__global__ void k_rope_apply(float* __restrict__ qkv, const float* __restrict__ tab) {
    int i = blockIdx.x * blockDim.x + threadIdx.x;  // NTOK*H*32
    if (i >= NTOK * HH * 32) return;
    int j  = i & 31;
    int h  = (i >> 5) % HH;
    int bt = i / (32 * HH);
    int t  = bt & (TT - 1);
    float cs = tab[(t * 32 + j) * 2];
    float sn = tab[(t * 32 + j) * 2 + 1];
    size_t base = (size_t)bt * (3 * CC) + h * SS + 2 * j;
    float qe = qkv[base], qo = qkv[base + 1];
    qkv[base]     = qe * cs - qo * sn;
    qkv[base + 1] = qo * cs + qe * sn;
    size_t kb = base + CC;
    float ke = qkv[kb], ko = qkv[kb + 1];
    qkv[kb]     = ke * cs - ko * sn;
    qkv[kb + 1] = ko * cs + ke * sn;
}

// ---------------- fp32 GEMM: C[M,N] = A[M,K] @ B[K,N] (+bias)(+res) -------
// 128x128 tile, BK=16, 256 threads, 8x8 microtile
template<bool BIAS, bool RES>
__global__ __launch_bounds__(256) void k_gemm(
    const float* __restrict__ A, const float* __restrict__ Bm,
    const float* __restrict__ bias, const float* __restrict__ res,
    float* __restrict__ C, int M, int N, int K)
{
    __shared__ float At[16][132];
    __shared__ float Bt[16][132];
    const int tid = threadIdx.x;
    const int row0 = blockIdx.y * 128, col0 = blockIdx.x * 128;
    const int ty = tid >> 4, tx = tid & 15;
    float acc[8][8];
#pragma unroll
    for (int i = 0; i < 8; ++i)
#pragma unroll
        for (int j = 0; j < 8; ++j) acc[i][j] = 0.f;

    for (int k0 = 0; k0 < K; k0 += 16) {
#pragma unroll
        for (int q = 0; q < 2; ++q) {
            int lin = q * 1024 + tid * 4;
            int r = lin >> 4, kk = lin & 15;  // kk in {0,4,8,12}
            float4 a4 = *(const float4*)(A + (size_t)(row0 + r) * K + k0 + kk);
            At[kk + 0][r] = a4.x; At[kk + 1][r] = a4.y;
            At[kk + 2][r] = a4.z; At[kk + 3][r] = a4.w;
        }
#pragma unroll
        for (int q = 0; q < 2; ++q) {
            int lin = q * 1024 + tid * 4;
            int kk = lin >> 7, c = lin & 127;
            *(float4*)&Bt[kk][c] = *(const float4*)(Bm + (size_t)(k0 + kk) * N + col0 + c);
        }
        __syncthreads();
#pragma unroll
        for (int kk = 0; kk < 16; ++kk) {
            float a[8], b[8];
            *(float4*)&a[0] = *(const float4*)&At[kk][ty * 8];
            *(float4*)&a[4] = *(const float4*)&At[kk][ty * 8 + 4];
            *(float4*)&b[0] = *(const float4*)&Bt[kk][tx * 8];
            *(float4*)&b[4] = *(const float4*)&Bt[kk][tx * 8 + 4];
#pragma unroll
            for (int i = 0; i < 8; ++i)
#pragma unroll
                for (int j = 0; j < 8; ++j)
                    acc[i][j] = fmaf(a[i], b[j], acc[i][j]);
        }
        __syncthreads();
    }
#pragma unroll
    for (int i = 0; i < 8; ++i) {
        int r = row0 + ty * 8 + i;
        size_t rowbase = (size_t)r * N + col0 + tx * 8;
#pragma unroll
        for (int j = 0; j < 8; j += 4) {
            float4 v = *(float4*)&acc[i][j];
            if (BIAS) {
                float4 bb = *(const float4*)(bias + col0 + tx * 8 + j);
                v.x += bb.x; v.y += bb.y; v.z += bb.z; v.w += bb.w;
            }
            if (RES) {
                float4 rr = *(const float4*)(res + rowbase + j);
                v.x += rr.x; v.y += rr.y; v.z += rr.z; v.w += rr.w;
            }
            *(float4*)(C + rowbase + j) = v;
        }
    }
}

// ---------------- flash attention (causal, online softmax) ----------------
// one block: 32 query rows of one (b,h); 256 threads = 32 rowgroups x 8
__global__ __launch_bounds__(256) void k_attn(
    const float* __restrict__ qkv, float* __restrict__ attn)
{
    __shared__ float Qs[QB][68];
    __shared__ float Ks[64][68];
    __shared__ float Vs[64][68];
    __shared__ float Ps[QB][68];
    const int tid = threadIdx.x;
    const int bh = blockIdx.x;
    const int b = bh / HH, h = bh % HH;
    const int qb = blockIdx.y * QB;
    const int r = tid >> 3, g = tid & 7;
    const float scale = 0.03608439182435161f;  // 768^-0.5

    // stage Q (pre-scaled)
#pragma unroll
    for (int q = 0; q < 2; ++q) {
        int lin = q * 1024 + tid * 4;
        int rr = lin >> 6, ss = lin & 63;
        float4 v = *(const float4*)(qkv + (size_t)(b * TT + qb + rr) * (3 * CC) + h * SS + ss);
        Qs[rr][ss]     = v.x * scale; Qs[rr][ss + 1] = v.y * scale;
        Qs[rr][ss + 2] = v.z * scale; Qs[rr][ss + 3] = v.w * scale;
    }

    float m = -INFINITY, l = 0.f;
    float acc[8] = {0.f, 0.f, 0.f, 0.f, 0.f, 0.f, 0.f, 0.f};
    const int qq = qb + r;
    const int nkt = (qb + QB - 1) / 64 + 1;

    for (int kt = 0; kt < nkt; ++kt) {
        __syncthreads();  // prev PV done (and Q staged, first iter)
        // stage K,V tile (64x64 each)
#pragma unroll
        for (int q = 0; q < 4; ++q) {
            int lin = q * 1024 + tid * 4;
            int rr = lin >> 6, ss = lin & 63;
            size_t gk = (size_t)(b * TT + kt * 64 + rr) * (3 * CC) + CC + h * SS + ss;
            float4 kv = *(const float4*)(qkv + gk);
            Ks[rr][ss] = kv.x; Ks[rr][ss + 1] = kv.y; Ks[rr][ss + 2] = kv.z; Ks[rr][ss + 3] = kv.w;
            float4 vv = *(const float4*)(qkv + gk + CC);
            Vs[rr][ss] = vv.x; Vs[rr][ss + 1] = vv.y; Vs[rr][ss + 2] = vv.z; Vs[rr][ss + 3] = vv.w;
        }
        __syncthreads();

        // scores: thread handles j = g + jj*8
        float sv[8];
#pragma unroll
        for (int jj = 0; jj < 8; ++jj) sv[jj] = 0.f;
#pragma unroll 4
        for (int ss = 0; ss < 64; ss += 4) {
            float4 qv = *(const float4*)&Qs[r][ss];
#pragma unroll
            for (int jj = 0; jj < 8; ++jj) {
                float4 kv = *(const float4*)&Ks[g + jj * 8][ss];
                sv[jj] = fmaf(qv.x, kv.x, fmaf(qv.y, kv.y, fmaf(qv.z, kv.z, fmaf(qv.w, kv.w, sv[jj]))));
            }
        }
        int kbase = kt * 64;
        float mx = -INFINITY;
#pragma unroll
        for (int jj = 0; jj < 8; ++jj) {
            if (kbase + g + jj * 8 > qq) sv[jj] = -INFINITY;
            mx = fmaxf(mx, sv[jj]);
        }
        mx = fmaxf(mx, __shfl_xor(mx, 1));
        mx = fmaxf(mx, __shfl_xor(mx, 2));
        mx = fmaxf(mx, __shfl_xor(mx, 4));
        float newm = fmaxf(m, mx);          // finite from tile 0 onward
        float corr = __expf(m - newm);      // m=-inf first tile -> 0
        float ps = 0.f;
#pragma unroll
        for (int jj = 0; jj < 8; ++jj) {
            float p = __expf(sv[jj] - newm);
            sv[jj] = p;
            ps += p;
        }
        ps += __shfl_xor(ps, 1);
        ps += __shfl_xor(ps, 2);
        ps += __shfl_xor(ps, 4);
        l = l * corr + ps;
        m = newm;
#pragma unroll
        for (int q2 = 0; q2 < 8; ++q2) acc[q2] *= corr;
#pragma unroll
        for (int jj = 0; jj < 8; ++jj) Ps[r][g + jj * 8] = sv[jj];
        __syncthreads();

        // PV: thread owns cols g*8 .. g*8+7
        for (int j0 = 0; j0 < 64; j0 += 4) {
            float pvals[4];
            *(float4*)pvals = *(const float4*)&Ps[r][j0];
#pragma unroll
            for (int d = 0; d < 4; ++d) {
                float p = pvals[d];
                float4 v0 = *(const float4*)&Vs[j0 + d][g * 8];
                float4 v1 = *(const float4*)&Vs[j0 + d][g * 8 + 4];
                acc[0] = fmaf(p, v0.x, acc[0]); acc[1] = fmaf(p, v0.y, acc[1]);
                acc[2] = fmaf(p, v0.z, acc[2]); acc[3] = fmaf(p, v0.w, acc[3]);
                acc[4] = fmaf(p, v1.x, acc[4]); acc[5] = fmaf(p, v1.y, acc[5]);
                acc[6] = fmaf(p, v1.z, acc[6]); acc[7] = fmaf(p, v1.w, acc[7]);
            }
        }
    }

    float inv = 1.0f / l;
    size_t ob = (size_t)(b * TT + qq) * CC + h * SS + g * 8;
#pragma unroll
    for (int q2 = 0; q2 < 8; ++q2) attn[ob + q2] = acc[q2] * inv;
}

// ---------------- swiglu: wx = wx * vx * sigmoid(vx) ----------------------
__global__ void k_swiglu(float* __restrict__ wx, const float* __restrict__ vx, int n4) {
    int i = blockIdx.x * blockDim.x + threadIdx.x;
    if (i >= n4) return;
    float4 w = ((float4*)wx)[i];
    float4 v = ((const float4*)vx)[i];
    w.x = w.x * v.x / (1.f + __expf(-v.x));
    w.y = w.y * v.y / (1.f + __expf(-v.y));
    w.z = w.z * v.z / (1.f + __expf(-v.z));
    w.w = w.w * v.w / (1.f + __expf(-v.w));
    ((float4*)wx)[i] = w;
}

// ---------------- launch ---------------------------------------------------
extern "C" void kernel_launch(void* const* d_in, const int* in_sizes, int n_in,
                              void* d_out, int out_size, void* d_ws, size_t ws_size,
                              hipStream_t stream)
{
    const float* x  = (const float*)d_in[0];
    const float* Wq = (const float*)d_in[1];
    const float* Wk = (const float*)d_in[2];
    const float* Wv = (const float*)d_in[3];
    const float* Wo = (const float*)d_in[4];
    const float* g1 = (const float*)d_in[5];
    const float* g2 = (const float*)d_in[6];
    const float* W1 = (const float*)d_in[7];
    const float* b1 = (const float*)d_in[8];
    const float* Ww = (const float*)d_in[9];
    const float* bw = (const float*)d_in[10];
    const float* Wg = (const float*)d_in[11];
    const float* bg = (const float*)d_in[12];
    const float* Wd = (const float*)d_in[13];
    const float* bd = (const float*)d_in[14];
    const float* W2 = (const float*)d_in[15];
    const float* b2 = (const float*)d_in[16];
    float* out = (float*)d_out;
    float* ws  = (float*)d_ws;

    // workspace layout (floats)
    float* scales = ws;                       // [0]=scale1 [1]=scale2
    float* part   = ws + 16;                  // 1024
    float* wpk    = ws + 2048;                // 768*2304 = 1769472
    float* tab    = wpk + 768 * 2304;         // 65536
    float* hbuf   = tab + 65536;              // 3145728
    float* qkv    = hbuf + (size_t)NTOK * CC; // 4096*2304 = 9437184
    float* attn   = qkv + (size_t)NTOK * 3 * CC;   // 3145728
    float* ubuf   = attn + (size_t)NTOK * CC;      // 12582912 (reused for ffmid)
    float* wxb    = ubuf + (size_t)NTOK * FFD;     // 8388608
    float* vxb    = wxb + (size_t)NTOK * HIDD;     // 8388608

    const int n = NTOK * CC;  // 3145728

    // rms1 scale
    k_sumsq_partial<<<1024, 256, 0, stream>>>(x, part, n / 4);
    k_sumsq_final<<<1, 256, 0, stream>>>(part, scales + 0, 1024, 1.0f / (float)n);
    k_scale_gamma<<<n / 4 / 256, 256, 0, stream>>>(x, g1, scales + 0, hbuf, n / 4);

    // pack qkv weights, rope table
    k_repack<<<(HH * CC * SS + 255) / 256, 256, 0, stream>>>(Wq, wpk, 0);
    k_repack<<<(HH * CC * SS + 255) / 256, 256, 0, stream>>>(Wk, wpk, CC);
    k_repack<<<(HH * CC * SS + 255) / 256, 256, 0, stream>>>(Wv, wpk, 2 * CC);
    k_rope_table<<<(TT * 32) / 256, 256, 0, stream>>>(tab);

    // qkv = h @ wpk   [4096, 2304]
    {
        dim3 grid(2304 / 128, NTOK / 128);
        k_gemm<false, false><<<grid, 256, 0, stream>>>(hbuf, wpk, nullptr, nullptr, qkv,
                                                       NTOK, 3 * CC, CC);
    }
    k_rope_apply<<<(NTOK * HH * 32) / 256, 256, 0, stream>>>(qkv, tab);

    // attention
    {
        dim3 grid(BB * HH, TT / QB);
        k_attn<<<grid, 256, 0, stream>>>(qkv, attn);
    }

    // out1 = attn @ Wo + x  -> d_out
    {
        dim3 grid(CC / 128, NTOK / 128);
        k_gemm<false, true><<<grid, 256, 0, stream>>>(attn, Wo, nullptr, x, out,
                                                      NTOK, CC, CC);
    }

    // rms2 scale over out1
    k_sumsq_partial<<<1024, 256, 0, stream>>>(out, part, n / 4);
    k_sumsq_final<<<1, 256, 0, stream>>>(part, scales + 1, 1024, 1.0f / (float)n);
    k_scale_gamma<<<n / 4 / 256, 256, 0, stream>>>(out, g2, scales + 1, hbuf, n / 4);

    // u = h2 @ W1 + b1   [4096, 3072]
    {
        dim3 grid(FFD / 128, NTOK / 128);
        k_gemm<true, false><<<grid, 256, 0, stream>>>(hbuf, W1, b1, nullptr, ubuf,
                                                      NTOK, FFD, CC);
    }
    // wx = u @ Ww + bw ; vx = u @ Wg + bg   [4096, 2048]
    {
        dim3 grid(HIDD / 128, NTOK / 128);
        k_gemm<true, false><<<grid, 256, 0, stream>>>(ubuf, Ww, bw, nullptr, wxb,
                                                      NTOK, HIDD, FFD);
        k_gemm<true, false><<<grid, 256, 0, stream>>>(ubuf, Wg, bg, nullptr, vxb,
                                                      NTOK, HIDD, FFD);
    }
    // swiglu into wx
    k_swiglu<<<(NTOK * HIDD / 4) / 256, 256, 0, stream>>>(wxb, vxb, NTOK * HIDD / 4);

    // ffmid = sw @ Wd + bd  [4096, 3072]  (reuse ubuf)
    {
        dim3 grid(FFD / 128, NTOK / 128);
        k_gemm<true, false><<<grid, 256, 0, stream>>>(wxb, Wd, bd, nullptr, ubuf,
                                                      NTOK, FFD, HIDD);
    }
    // out = out1 + ffmid @ W2 + b2
    {
        dim3 grid(CC / 128, NTOK / 128);
        k_gemm<true, true><<<grid, 256, 0, stream>>>(ubuf, W2, b2, out, out,
                                                     NTOK, CC, FFD);
    }
}

// Round 2
// 612.710 us; speedup vs baseline: 4.9446x; 4.9446x over previous
//
#include <hip/hip_runtime.h>
#include <math.h>

#define BB   4
#define TT   1024
#define CC   768
#define HH   12
#define SS   64
#define FFD  3072
#define HIDD 2048
#define NTOK (BB*TT)          // 4096
#define EPSR 1e-6f
#define QB   32

typedef __attribute__((ext_vector_type(8))) short bf16x8;
typedef __attribute__((ext_vector_type(4))) float f32x4;

__device__ __forceinline__ unsigned short f2bf(float f) {
    unsigned u = __float_as_uint(f);
    return (unsigned short)((u + 0x7FFFu + ((u >> 16) & 1u)) >> 16);
}
__device__ __forceinline__ float bfl(unsigned u) { return __uint_as_float(u << 16); }
__device__ __forceinline__ float bfh(unsigned u) { return __uint_as_float(u & 0xFFFF0000u); }
__device__ __forceinline__ unsigned pk2(float a, float b) {
    return (unsigned)f2bf(a) | ((unsigned)f2bf(b) << 16);
}

__device__ __forceinline__ void gload_lds16(const unsigned short* g, unsigned short* l) {
    __builtin_amdgcn_global_load_lds(
        (const __attribute__((address_space(1))) unsigned int*)g,
        (__attribute__((address_space(3))) unsigned int*)l, 16, 0, 0);
}

// ---------------- global sum-of-squares (two-stage, deterministic) -------
__global__ void k_sumsq_partial(const float* __restrict__ x, float* __restrict__ part, int n4) {
    __shared__ float sm[256];
    float s = 0.f;
    int stride = gridDim.x * blockDim.x;
    for (int i = blockIdx.x * blockDim.x + threadIdx.x; i < n4; i += stride) {
        float4 v = ((const float4*)x)[i];
        s += v.x*v.x + v.y*v.y + v.z*v.z + v.w*v.w;
    }
    sm[threadIdx.x] = s;
    __syncthreads();
    for (int off = 128; off > 0; off >>= 1) {
        if (threadIdx.x < off) sm[threadIdx.x] += sm[threadIdx.x + off];
        __syncthreads();
    }
    if (threadIdx.x == 0) part[blockIdx.x] = sm[0];
}

__global__ void k_sumsq_final(const float* __restrict__ part, float* __restrict__ outscale,
                              int npart, float invn) {
    __shared__ float sm[256];
    float s = 0.f;
    for (int i = threadIdx.x; i < npart; i += 256) s += part[i];
    sm[threadIdx.x] = s;
    __syncthreads();
    for (int off = 128; off > 0; off >>= 1) {
        if (threadIdx.x < off) sm[threadIdx.x] += sm[threadIdx.x + off];
        __syncthreads();
    }
    if (threadIdx.x == 0) outscale[0] = 1.0f / sqrtf(EPSR + sm[0] * invn);
}

// ---------------- h_bf16 = bf16(x * scale * gamma[c]) ---------------------
__global__ void k_scale_gamma_b(const float* __restrict__ x, const float* __restrict__ g,
                                const float* __restrict__ scale, unsigned short* __restrict__ h,
                                int n8) {
    int i = blockIdx.x * blockDim.x + threadIdx.x;
    if (i >= n8) return;
    float sc = scale[0];
    float4 v0 = ((const float4*)x)[2*i];
    float4 v1 = ((const float4*)x)[2*i+1];
    int c = (i * 8) % CC;
    float4 g0 = *(const float4*)(g + c);
    float4 g1v = *(const float4*)(g + c + 4);
    uint4 r;
    r.x = pk2(v0.x*sc*g0.x,  v0.y*sc*g0.y);
    r.y = pk2(v0.z*sc*g0.z,  v0.w*sc*g0.w);
    r.z = pk2(v1.x*sc*g1v.x, v1.y*sc*g1v.y);
    r.w = pk2(v1.z*sc*g1v.z, v1.w*sc*g1v.w);
    ((uint4*)h)[i] = r;
}

// ---------------- weight transpose-convert: W[K][N] f32 -> Wt[N][K] bf16 --
__global__ void k_wT(const float* __restrict__ W, unsigned short* __restrict__ Wt,
                     int K, int N) {
    __shared__ float t[32][33];
    int k0 = blockIdx.x * 32, n0 = blockIdx.y * 32;
    int tx = threadIdx.x & 31, ty = threadIdx.x >> 5;
#pragma unroll
    for (int i = 0; i < 4; ++i)
        t[ty + i*8][tx] = W[(size_t)(k0 + ty + i*8) * N + n0 + tx];
    __syncthreads();
#pragma unroll
    for (int i = 0; i < 4; ++i)
        Wt[(size_t)(n0 + ty + i*8) * K + k0 + tx] = f2bf(t[tx][ty + i*8]);
}

// Wq/Wk/Wv [H][C][S] f32 -> packed WqkvT [3C][C] bf16 (row = sel*768+h*64+s)
__global__ void k_wqkvT(const float* __restrict__ Wq, const float* __restrict__ Wk,
                        const float* __restrict__ Wv, unsigned short* __restrict__ Wt) {
    __shared__ float t[32][33];
    int z = blockIdx.z, sel = z / HH, h = z % HH;
    const float* W = (sel == 0 ? Wq : (sel == 1 ? Wk : Wv)) + (size_t)h * CC * SS;
    int c0 = blockIdx.x * 32, s0 = blockIdx.y * 32;
    int tx = threadIdx.x & 31, ty = threadIdx.x >> 5;
#pragma unroll
    for (int i = 0; i < 4; ++i)
        t[ty + i*8][tx] = W[(size_t)(c0 + ty + i*8) * SS + s0 + tx];
    __syncthreads();
#pragma unroll
    for (int i = 0; i < 4; ++i)
        Wt[(size_t)(sel*CC + h*SS + s0 + ty + i*8) * CC + c0 + tx] = f2bf(t[tx][ty + i*8]);
}

// ---------------- rope cos/sin table [T][32][2] ----------------------------
__global__ void k_rope_table(float* __restrict__ tab) {
    int i = blockIdx.x * blockDim.x + threadIdx.x;
    if (i >= TT * 32) return;
    int t = i >> 5, j = i & 31;
    float th = expf(-(float)j * 0.5756462732485115f);  // 10000^(-j/16)
    float ang = (float)t * th;
    tab[2*i]   = cosf(ang);
    tab[2*i+1] = sinf(ang);
}

// ---------------- apply rope in-place to bf16 qkv --------------------------
__global__ void k_rope_apply_b(unsigned short* __restrict__ qkv, const float* __restrict__ tab) {
    int i = blockIdx.x * blockDim.x + threadIdx.x;  // NTOK*H*32
    if (i >= NTOK * HH * 32) return;
    int j  = i & 31;
    int h  = (i >> 5) % HH;
    int bt = i / (32 * HH);
    int t  = bt & (TT - 1);
    float cs = tab[(t*32 + j)*2];
    float sn = tab[(t*32 + j)*2 + 1];
    size_t base = (size_t)bt * (3*CC) + h * SS + 2*j;
    unsigned q = *(unsigned*)(qkv + base);
    float qe = bfl(q), qo = bfh(q);
    *(unsigned*)(qkv + base) = pk2(qe*cs - qo*sn, qo*cs + qe*sn);
    unsigned k = *(unsigned*)(qkv + base + CC);
    float ke = bfl(k), ko = bfh(k);
    *(unsigned*)(qkv + base + CC) = pk2(ke*cs - ko*sn, ko*cs + ke*sn);
}

// ---------------- bf16 MFMA GEMM: C[M,N] = A[M,K] @ Bt[N,K]^T --------------
// 128x128 tile, BK=32, 4 waves (2x2) of 64x64, double-buffered LDS,
// global_load_lds(16B) with source-side XOR swizzle; 2-phase pipeline.
template<bool BIAS, bool RES, bool OUTB>
__global__ __launch_bounds__(256) void k_gemm_bf16(
    const unsigned short* __restrict__ A, const unsigned short* __restrict__ Bt,
    const float* __restrict__ bias, const float* __restrict__ res,
    void* __restrict__ Cv, int M, int N, int K)
{
    __shared__ unsigned short As[2][128*32];
    __shared__ unsigned short Bs[2][128*32];
    const int tid  = threadIdx.x;
    const int w    = tid >> 6, lane = tid & 63;
    const int wr   = w >> 1,  wc   = w & 1;
    const int row0 = blockIdx.y * 128, col0 = blockIdx.x * 128;

    f32x4 acc[4][4];
#pragma unroll
    for (int m = 0; m < 4; ++m)
#pragma unroll
        for (int n = 0; n < 4; ++n) acc[m][n] = (f32x4){0.f, 0.f, 0.f, 0.f};

    const int lr4 = lane >> 2;   // row-within-issue 0..15
    const int scb = lane & 3;    // swizzled 16B slot

    auto stage = [&](int t, int buf) {
#pragma unroll
        for (int i = 0; i < 2; ++i) {
            int lr = w * 32 + i * 16 + lr4;                 // local row 0..127
            int cbs = scb ^ ((lr >> 1) & 3);                // source col-block
            const unsigned short* ga = A + (size_t)(row0 + lr) * K + t * 32 + cbs * 8;
            gload_lds16(ga, &As[buf][(w * 32 + i * 16) * 32]);
            const unsigned short* gb = Bt + (size_t)(col0 + lr) * K + t * 32 + cbs * 8;
            gload_lds16(gb, &Bs[buf][(w * 32 + i * 16) * 32]);
        }
    };

    const int nt = K / 32;
    stage(0, 0);
    int cur = 0;
    const int fr = lane & 15, fq = lane >> 4;
    for (int t = 0; t < nt; ++t) {
        __syncthreads();                       // drains vmcnt -> buf[cur] ready
        if (t + 1 < nt) stage(t + 1, cur ^ 1); // prefetch overlaps MFMA below
        bf16x8 af[4], bf[4];
#pragma unroll
        for (int m = 0; m < 4; ++m) {
            int ra = wr * 64 + m * 16 + fr;
            af[m] = *(const bf16x8*)&As[cur][ra * 32 + (fq ^ ((ra >> 1) & 3)) * 8];
            int rb = wc * 64 + m * 16 + fr;
            bf[m] = *(const bf16x8*)&Bs[cur][rb * 32 + (fq ^ ((rb >> 1) & 3)) * 8];
        }
#pragma unroll
        for (int m = 0; m < 4; ++m)
#pragma unroll
            for (int n = 0; n < 4; ++n)
                acc[m][n] = __builtin_amdgcn_mfma_f32_16x16x32_bf16(af[m], bf[n], acc[m][n], 0, 0, 0);
        cur ^= 1;
    }

    // epilogue: row = m*16 + fq*4 + j, col = n*16 + fr  (m89-verified mapping)
#pragma unroll
    for (int m = 0; m < 4; ++m) {
#pragma unroll
        for (int n = 0; n < 4; ++n) {
            int col = col0 + wc * 64 + n * 16 + fr;
            float bv = BIAS ? bias[col] : 0.f;
#pragma unroll
            for (int j = 0; j < 4; ++j) {
                int row = row0 + wr * 64 + m * 16 + fq * 4 + j;
                size_t off = (size_t)row * N + col;
                float v = acc[m][n][j] + bv;
                if (RES) v += res[off];
                if (OUTB) ((unsigned short*)Cv)[off] = f2bf(v);
                else      ((float*)Cv)[off] = v;
            }
        }
    }
}

// ---------------- flash attention (causal, online softmax), bf16 I/O ------
__global__ __launch_bounds__(256) void k_attn(
    const unsigned short* __restrict__ qkv, unsigned short* __restrict__ attn)
{
    __shared__ float Qs[QB][68];
    __shared__ float Ks[64][68];
    __shared__ float Vs[64][68];
    __shared__ float Ps[QB][68];
    const int tid = threadIdx.x;
    const int bh = blockIdx.x;
    const int b = bh / HH, h = bh % HH;
    const int qb = blockIdx.y * QB;
    const int r = tid >> 3, g = tid & 7;
    const float scale = 0.03608439182435161f;  // 768^-0.5

    // stage Q (pre-scaled): 32x64 = 2048 elems, 8 per thread
    {
        int lin = tid * 8;
        int rr = lin >> 6, ss = lin & 63;
        uint4 v = *(const uint4*)(qkv + (size_t)(b*TT + qb + rr)*(3*CC) + h*SS + ss);
        Qs[rr][ss+0] = bfl(v.x)*scale; Qs[rr][ss+1] = bfh(v.x)*scale;
        Qs[rr][ss+2] = bfl(v.y)*scale; Qs[rr][ss+3] = bfh(v.y)*scale;
        Qs[rr][ss+4] = bfl(v.z)*scale; Qs[rr][ss+5] = bfh(v.z)*scale;
        Qs[rr][ss+6] = bfl(v.w)*scale; Qs[rr][ss+7] = bfh(v.w)*scale;
    }

    float m = -INFINITY, l = 0.f;
    float acc[8] = {0.f,0.f,0.f,0.f,0.f,0.f,0.f,0.f};
    const int qq = qb + r;
    const int nkt = (qb + QB - 1) / 64 + 1;

    for (int kt = 0; kt < nkt; ++kt) {
        __syncthreads();
        // stage K,V tile (64x64 each), 8 elems per thread per pass
#pragma unroll
        for (int p = 0; p < 2; ++p) {
            int lin = p * 2048 + tid * 8;
            int rr = lin >> 6, ss = lin & 63;
            size_t gk = (size_t)(b*TT + kt*64 + rr)*(3*CC) + CC + h*SS + ss;
            uint4 kv = *(const uint4*)(qkv + gk);
            Ks[rr][ss+0]=bfl(kv.x); Ks[rr][ss+1]=bfh(kv.x);
            Ks[rr][ss+2]=bfl(kv.y); Ks[rr][ss+3]=bfh(kv.y);
            Ks[rr][ss+4]=bfl(kv.z); Ks[rr][ss+5]=bfh(kv.z);
            Ks[rr][ss+6]=bfl(kv.w); Ks[rr][ss+7]=bfh(kv.w);
            uint4 vv = *(const uint4*)(qkv + gk + CC);
            Vs[rr][ss+0]=bfl(vv.x); Vs[rr][ss+1]=bfh(vv.x);
            Vs[rr][ss+2]=bfl(vv.y); Vs[rr][ss+3]=bfh(vv.y);
            Vs[rr][ss+4]=bfl(vv.z); Vs[rr][ss+5]=bfh(vv.z);
            Vs[rr][ss+6]=bfl(vv.w); Vs[rr][ss+7]=bfh(vv.w);
        }
        __syncthreads();

        float sv[8];
#pragma unroll
        for (int jj = 0; jj < 8; ++jj) sv[jj] = 0.f;
#pragma unroll 4
        for (int ss = 0; ss < 64; ss += 4) {
            float4 qv = *(const float4*)&Qs[r][ss];
#pragma unroll
            for (int jj = 0; jj < 8; ++jj) {
                float4 kv = *(const float4*)&Ks[g + jj*8][ss];
                sv[jj] = fmaf(qv.x, kv.x, fmaf(qv.y, kv.y, fmaf(qv.z, kv.z, fmaf(qv.w, kv.w, sv[jj]))));
            }
        }
        int kbase = kt * 64;
        float mx = -INFINITY;
#pragma unroll
        for (int jj = 0; jj < 8; ++jj) {
            if (kbase + g + jj*8 > qq) sv[jj] = -INFINITY;
            mx = fmaxf(mx, sv[jj]);
        }
        mx = fmaxf(mx, __shfl_xor(mx, 1));
        mx = fmaxf(mx, __shfl_xor(mx, 2));
        mx = fmaxf(mx, __shfl_xor(mx, 4));
        float newm = fmaxf(m, mx);
        float corr = __expf(m - newm);
        float ps = 0.f;
#pragma unroll
        for (int jj = 0; jj < 8; ++jj) {
            float pv = __expf(sv[jj] - newm);
            sv[jj] = pv;
            ps += pv;
        }
        ps += __shfl_xor(ps, 1);
        ps += __shfl_xor(ps, 2);
        ps += __shfl_xor(ps, 4);
        l = l * corr + ps;
        m = newm;
#pragma unroll
        for (int q2 = 0; q2 < 8; ++q2) acc[q2] *= corr;
#pragma unroll
        for (int jj = 0; jj < 8; ++jj) Ps[r][g + jj*8] = sv[jj];
        __syncthreads();

        for (int j0 = 0; j0 < 64; j0 += 4) {
            float pv4[4];
            *(float4*)pv4 = *(const float4*)&Ps[r][j0];
#pragma unroll
            for (int d = 0; d < 4; ++d) {
                float pv = pv4[d];
                float4 v0 = *(const float4*)&Vs[j0+d][g*8];
                float4 v1 = *(const float4*)&Vs[j0+d][g*8+4];
                acc[0] = fmaf(pv, v0.x, acc[0]); acc[1] = fmaf(pv, v0.y, acc[1]);
                acc[2] = fmaf(pv, v0.z, acc[2]); acc[3] = fmaf(pv, v0.w, acc[3]);
                acc[4] = fmaf(pv, v1.x, acc[4]); acc[5] = fmaf(pv, v1.y, acc[5]);
                acc[6] = fmaf(pv, v1.z, acc[6]); acc[7] = fmaf(pv, v1.w, acc[7]);
            }
        }
    }

    float inv = 1.0f / l;
    size_t ob = (size_t)(b*TT + qq) * CC + h*SS + g*8;
    uint4 st;
    st.x = pk2(acc[0]*inv, acc[1]*inv);
    st.y = pk2(acc[2]*inv, acc[3]*inv);
    st.z = pk2(acc[4]*inv, acc[5]*inv);
    st.w = pk2(acc[6]*inv, acc[7]*inv);
    *(uint4*)(attn + ob) = st;
}

// ---------------- swiglu: sw = bf16(wx * vx * sigmoid(vx)) ----------------
__global__ void k_swiglu_b(const unsigned short* __restrict__ wx,
                           const unsigned short* __restrict__ vx,
                           unsigned short* __restrict__ sw, int n8) {
    int i = blockIdx.x * blockDim.x + threadIdx.x;
    if (i >= n8) return;
    uint4 wv = ((const uint4*)wx)[i];
    uint4 vv = ((const uint4*)vx)[i];
    uint4 r;
    float w0, w1, v0, v1;
    w0 = bfl(wv.x); w1 = bfh(wv.x); v0 = bfl(vv.x); v1 = bfh(vv.x);
    r.x = pk2(w0*v0/(1.f+__expf(-v0)), w1*v1/(1.f+__expf(-v1)));
    w0 = bfl(wv.y); w1 = bfh(wv.y); v0 = bfl(vv.y); v1 = bfh(vv.y);
    r.y = pk2(w0*v0/(1.f+__expf(-v0)), w1*v1/(1.f+__expf(-v1)));
    w0 = bfl(wv.z); w1 = bfh(wv.z); v0 = bfl(vv.z); v1 = bfh(vv.z);
    r.z = pk2(w0*v0/(1.f+__expf(-v0)), w1*v1/(1.f+__expf(-v1)));
    w0 = bfl(wv.w); w1 = bfh(wv.w); v0 = bfl(vv.w); v1 = bfh(vv.w);
    r.w = pk2(w0*v0/(1.f+__expf(-v0)), w1*v1/(1.f+__expf(-v1)));
    ((uint4*)sw)[i] = r;
}

// ---------------- launch ---------------------------------------------------
extern "C" void kernel_launch(void* const* d_in, const int* in_sizes, int n_in,
                              void* d_out, int out_size, void* d_ws, size_t ws_size,
                              hipStream_t stream)
{
    const float* x  = (const float*)d_in[0];
    const float* Wq = (const float*)d_in[1];
    const float* Wk = (const float*)d_in[2];
    const float* Wv = (const float*)d_in[3];
    const float* Wo = (const float*)d_in[4];
    const float* g1 = (const float*)d_in[5];
    const float* g2 = (const float*)d_in[6];
    const float* W1 = (const float*)d_in[7];
    const float* b1 = (const float*)d_in[8];
    const float* Ww = (const float*)d_in[9];
    const float* bw = (const float*)d_in[10];
    const float* Wg = (const float*)d_in[11];
    const float* bg = (const float*)d_in[12];
    const float* Wd = (const float*)d_in[13];
    const float* bd = (const float*)d_in[14];
    const float* W2 = (const float*)d_in[15];
    const float* b2 = (const float*)d_in[16];
    float* out = (float*)d_out;

    // bump allocator over d_ws
    char* p = (char*)d_ws;
    auto alloc = [&](size_t bytes) { char* r = p; p += (bytes + 255) & ~(size_t)255; return r; };

    float*          scales = (float*)alloc(256);
    float*          part   = (float*)alloc(4096);
    float*          tab    = (float*)alloc((size_t)TT*32*2*4);
    unsigned short* hb     = (unsigned short*)alloc((size_t)NTOK*CC*2);
    unsigned short* wqkvT  = (unsigned short*)alloc((size_t)3*CC*CC*2);
    unsigned short* qkvb   = (unsigned short*)alloc((size_t)NTOK*3*CC*2);
    unsigned short* attnb  = (unsigned short*)alloc((size_t)NTOK*CC*2);
    unsigned short* WoT    = (unsigned short*)alloc((size_t)CC*CC*2);
    unsigned short* W1T    = (unsigned short*)alloc((size_t)FFD*CC*2);
    unsigned short* ub     = (unsigned short*)alloc((size_t)NTOK*FFD*2);   // also ffb
    unsigned short* WwT    = (unsigned short*)alloc((size_t)HIDD*FFD*2);
    unsigned short* WgT    = (unsigned short*)alloc((size_t)HIDD*FFD*2);
    unsigned short* wxb    = (unsigned short*)alloc((size_t)NTOK*HIDD*2);
    unsigned short* vxb    = (unsigned short*)alloc((size_t)NTOK*HIDD*2);
    unsigned short* swb    = (unsigned short*)alloc((size_t)NTOK*HIDD*2);
    unsigned short* WdT    = (unsigned short*)alloc((size_t)FFD*HIDD*2);
    unsigned short* W2T    = (unsigned short*)alloc((size_t)CC*FFD*2);

    const int n = NTOK * CC;  // 3145728

    // weight conversions + rope table
    k_wqkvT<<<dim3(CC/32, SS/32, 36), 256, 0, stream>>>(Wq, Wk, Wv, wqkvT);
    k_wT<<<dim3(CC/32,  CC/32),  256, 0, stream>>>(Wo, WoT, CC,  CC);
    k_wT<<<dim3(CC/32,  FFD/32), 256, 0, stream>>>(W1, W1T, CC,  FFD);
    k_wT<<<dim3(FFD/32, HIDD/32),256, 0, stream>>>(Ww, WwT, FFD, HIDD);
    k_wT<<<dim3(FFD/32, HIDD/32),256, 0, stream>>>(Wg, WgT, FFD, HIDD);
    k_wT<<<dim3(HIDD/32,FFD/32), 256, 0, stream>>>(Wd, WdT, HIDD,FFD);
    k_wT<<<dim3(FFD/32, CC/32),  256, 0, stream>>>(W2, W2T, FFD, CC);
    k_rope_table<<<(TT*32)/256, 256, 0, stream>>>(tab);

    // rms1 -> h (bf16)
    k_sumsq_partial<<<1024, 256, 0, stream>>>(x, part, n/4);
    k_sumsq_final<<<1, 256, 0, stream>>>(part, scales + 0, 1024, 1.0f/(float)n);
    k_scale_gamma_b<<<(n/8)/256, 256, 0, stream>>>(x, g1, scales + 0, hb, n/8);

    // qkv = h @ WqkvT^T  [4096, 2304] bf16
    k_gemm_bf16<false,false,true><<<dim3(3*CC/128, NTOK/128), 256, 0, stream>>>(
        hb, wqkvT, nullptr, nullptr, qkvb, NTOK, 3*CC, CC);
    k_rope_apply_b<<<(NTOK*HH*32)/256, 256, 0, stream>>>(qkvb, tab);

    // attention -> attnb (bf16)
    k_attn<<<dim3(BB*HH, TT/QB), 256, 0, stream>>>(qkvb, attnb);

    // out1 = attn @ Wo + x  (fp32, in d_out)
    k_gemm_bf16<false,true,false><<<dim3(CC/128, NTOK/128), 256, 0, stream>>>(
        attnb, WoT, nullptr, x, out, NTOK, CC, CC);

    // rms2 -> h2 (bf16, reuse hb)
    k_sumsq_partial<<<1024, 256, 0, stream>>>(out, part, n/4);
    k_sumsq_final<<<1, 256, 0, stream>>>(part, scales + 1, 1024, 1.0f/(float)n);
    k_scale_gamma_b<<<(n/8)/256, 256, 0, stream>>>(out, g2, scales + 1, hb, n/8);

    // u = h2 @ W1 + b1  -> bf16
    k_gemm_bf16<true,false,true><<<dim3(FFD/128, NTOK/128), 256, 0, stream>>>(
        hb, W1T, b1, nullptr, ub, NTOK, FFD, CC);
    // wx / vx -> bf16
    k_gemm_bf16<true,false,true><<<dim3(HIDD/128, NTOK/128), 256, 0, stream>>>(
        ub, WwT, bw, nullptr, wxb, NTOK, HIDD, FFD);
    k_gemm_bf16<true,false,true><<<dim3(HIDD/128, NTOK/128), 256, 0, stream>>>(
        ub, WgT, bg, nullptr, vxb, NTOK, HIDD, FFD);
    // swiglu -> swb (bf16)
    k_swiglu_b<<<(NTOK*HIDD/8)/256, 256, 0, stream>>>(wxb, vxb, swb, NTOK*HIDD/8);
    // ffmid = sw @ Wd + bd -> bf16 (reuse ub)
    k_gemm_bf16<true,false,true><<<dim3(FFD/128, NTOK/128), 256, 0, stream>>>(
        swb, WdT, bd, nullptr, ub, NTOK, FFD, HIDD);
    // out = out1 + ffmid @ W2 + b2  (fp32)
    k_gemm_bf16<true,true,false><<<dim3(CC/128, NTOK/128), 256, 0, stream>>>(
        ub, W2T, b2, out, out, NTOK, CC, FFD);
}

// Round 3
// 466.108 us; speedup vs baseline: 6.4999x; 1.3145x over previous
//
#include <hip/hip_runtime.h>
#include <math.h>

#define BB   4
#define TT   1024
#define CC   768
#define HH   12
#define SS   64
#define FFD  3072
#define HIDD 2048
#define NTOK (BB*TT)          // 4096
#define EPSR 1e-6f

typedef __attribute__((ext_vector_type(8))) short bf16x8;
typedef __attribute__((ext_vector_type(4))) float f32x4;

__device__ __forceinline__ unsigned short f2bf(float f) {
    unsigned u = __float_as_uint(f);
    return (unsigned short)((u + 0x7FFFu + ((u >> 16) & 1u)) >> 16);
}
__device__ __forceinline__ float bfl(unsigned u) { return __uint_as_float(u << 16); }
__device__ __forceinline__ float bfh(unsigned u) { return __uint_as_float(u & 0xFFFF0000u); }
__device__ __forceinline__ unsigned pk2(float a, float b) {
    return (unsigned)f2bf(a) | ((unsigned)f2bf(b) << 16);
}

__device__ __forceinline__ void gload_lds16(const unsigned short* g, unsigned short* l) {
    __builtin_amdgcn_global_load_lds(
        (const __attribute__((address_space(1))) unsigned int*)g,
        (__attribute__((address_space(3))) unsigned int*)l, 16, 0, 0);
}

// ---------------- global sum-of-squares (two-stage, deterministic) -------
__global__ void k_sumsq_partial(const float* __restrict__ x, float* __restrict__ part, int n4) {
    __shared__ float sm[256];
    float s = 0.f;
    int stride = gridDim.x * blockDim.x;
    for (int i = blockIdx.x * blockDim.x + threadIdx.x; i < n4; i += stride) {
        float4 v = ((const float4*)x)[i];
        s += v.x*v.x + v.y*v.y + v.z*v.z + v.w*v.w;
    }
    sm[threadIdx.x] = s;
    __syncthreads();
    for (int off = 128; off > 0; off >>= 1) {
        if (threadIdx.x < off) sm[threadIdx.x] += sm[threadIdx.x + off];
        __syncthreads();
    }
    if (threadIdx.x == 0) part[blockIdx.x] = sm[0];
}

__global__ void k_sumsq_final(const float* __restrict__ part, float* __restrict__ outscale,
                              int npart, float invn) {
    __shared__ float sm[256];
    float s = 0.f;
    for (int i = threadIdx.x; i < npart; i += 256) s += part[i];
    sm[threadIdx.x] = s;
    __syncthreads();
    for (int off = 128; off > 0; off >>= 1) {
        if (threadIdx.x < off) sm[threadIdx.x] += sm[threadIdx.x + off];
        __syncthreads();
    }
    if (threadIdx.x == 0) outscale[0] = 1.0f / sqrtf(EPSR + sm[0] * invn);
}

// ---------------- h_bf16 = bf16(x * scale * gamma[c]) ---------------------
__global__ void k_scale_gamma_b(const float* __restrict__ x, const float* __restrict__ g,
                                const float* __restrict__ scale, unsigned short* __restrict__ h,
                                int n8) {
    int i = blockIdx.x * blockDim.x + threadIdx.x;
    if (i >= n8) return;
    float sc = scale[0];
    float4 v0 = ((const float4*)x)[2*i];
    float4 v1 = ((const float4*)x)[2*i+1];
    int c = (i * 8) % CC;
    float4 g0 = *(const float4*)(g + c);
    float4 g1v = *(const float4*)(g + c + 4);
    uint4 r;
    r.x = pk2(v0.x*sc*g0.x,  v0.y*sc*g0.y);
    r.y = pk2(v0.z*sc*g0.z,  v0.w*sc*g0.w);
    r.z = pk2(v1.x*sc*g1v.x, v1.y*sc*g1v.y);
    r.w = pk2(v1.z*sc*g1v.z, v1.w*sc*g1v.w);
    ((uint4*)h)[i] = r;
}

// ---------------- weight transpose-convert: W[K][N] f32 -> Wt[N][K] bf16 --
__global__ void k_wT(const float* __restrict__ W, unsigned short* __restrict__ Wt,
                     int K, int N) {
    __shared__ float t[32][33];
    int k0 = blockIdx.x * 32, n0 = blockIdx.y * 32;
    int tx = threadIdx.x & 31, ty = threadIdx.x >> 5;
#pragma unroll
    for (int i = 0; i < 4; ++i)
        t[ty + i*8][tx] = W[(size_t)(k0 + ty + i*8) * N + n0 + tx];
    __syncthreads();
#pragma unroll
    for (int i = 0; i < 4; ++i)
        Wt[(size_t)(n0 + ty + i*8) * K + k0 + tx] = f2bf(t[tx][ty + i*8]);
}

// Wq/Wk/Wv [H][C][S] f32 -> packed WqkvT [3C][C] bf16 (row = sel*768+h*64+s)
__global__ void k_wqkvT(const float* __restrict__ Wq, const float* __restrict__ Wk,
                        const float* __restrict__ Wv, unsigned short* __restrict__ Wt) {
    __shared__ float t[32][33];
    int z = blockIdx.z, sel = z / HH, h = z % HH;
    const float* W = (sel == 0 ? Wq : (sel == 1 ? Wk : Wv)) + (size_t)h * CC * SS;
    int c0 = blockIdx.x * 32, s0 = blockIdx.y * 32;
    int tx = threadIdx.x & 31, ty = threadIdx.x >> 5;
#pragma unroll
    for (int i = 0; i < 4; ++i)
        t[ty + i*8][tx] = W[(size_t)(c0 + ty + i*8) * SS + s0 + tx];
    __syncthreads();
#pragma unroll
    for (int i = 0; i < 4; ++i)
        Wt[(size_t)(sel*CC + h*SS + s0 + ty + i*8) * CC + c0 + tx] = f2bf(t[tx][ty + i*8]);
}

// ---------------- rope cos/sin table [T][32][2] ----------------------------
__global__ void k_rope_table(float* __restrict__ tab) {
    int i = blockIdx.x * blockDim.x + threadIdx.x;
    if (i >= TT * 32) return;
    int t = i >> 5, j = i & 31;
    float th = expf(-(float)j * 0.5756462732485115f);  // 10000^(-j/16)
    float ang = (float)t * th;
    tab[2*i]   = cosf(ang);
    tab[2*i+1] = sinf(ang);
}

// ---------------- apply rope in-place to bf16 qkv --------------------------
__global__ void k_rope_apply_b(unsigned short* __restrict__ qkv, const float* __restrict__ tab) {
    int i = blockIdx.x * blockDim.x + threadIdx.x;  // NTOK*H*32
    if (i >= NTOK * HH * 32) return;
    int j  = i & 31;
    int h  = (i >> 5) % HH;
    int bt = i / (32 * HH);
    int t  = bt & (TT - 1);
    float cs = tab[(t*32 + j)*2];
    float sn = tab[(t*32 + j)*2 + 1];
    size_t base = (size_t)bt * (3*CC) + h * SS + 2*j;
    unsigned q = *(unsigned*)(qkv + base);
    float qe = bfl(q), qo = bfh(q);
    *(unsigned*)(qkv + base) = pk2(qe*cs - qo*sn, qo*cs + qe*sn);
    unsigned k = *(unsigned*)(qkv + base + CC);
    float ke = bfl(k), ko = bfh(k);
    *(unsigned*)(qkv + base + CC) = pk2(ke*cs - ko*sn, ko*cs + ke*sn);
}

// ---------------- V transpose: qkv V part -> vtg[bh][64][T] ---------------
// thread: d = tid&63, tq = tid>>6; 32 t-values each; coalesced loads (lane=d)
// and full-line 64B stores (4 uint4 along t).
__global__ void k_vT(const unsigned short* __restrict__ qkv, unsigned short* __restrict__ vtg) {
    int bh = blockIdx.x, ty = blockIdx.y;  // grid (48, TT/128)
    int b = bh / HH, h = bh % HH;
    int d = threadIdx.x & 63, tq = threadIdx.x >> 6;
    int t0 = ty * 128 + tq * 32;
    const unsigned short* src = qkv + (size_t)(b*TT + t0)*(3*CC) + 2*CC + h*SS + d;
    unsigned v[16];
#pragma unroll
    for (int e = 0; e < 16; ++e) {
        unsigned lo = src[(size_t)(2*e)*(3*CC)];
        unsigned hi = src[(size_t)(2*e+1)*(3*CC)];
        v[e] = (lo & 0xFFFFu) | (hi << 16);
    }
    uint4* dst = (uint4*)(vtg + ((size_t)bh*64 + d)*TT + t0);
#pragma unroll
    for (int q = 0; q < 4; ++q)
        dst[q] = make_uint4(v[q*4], v[q*4+1], v[q*4+2], v[q*4+3]);
}

// ---------------- bf16 MFMA GEMM: C[M,N] = A[M,K] @ Bt[N,K]^T --------------
template<bool BIAS, bool RES, bool OUTB>
__global__ __launch_bounds__(256) void k_gemm_bf16(
    const unsigned short* __restrict__ A, const unsigned short* __restrict__ Bt,
    const float* __restrict__ bias, const float* __restrict__ res,
    void* __restrict__ Cv, int M, int N, int K)
{
    __shared__ unsigned short As[2][128*32];
    __shared__ unsigned short Bs[2][128*32];
    const int tid  = threadIdx.x;
    const int w    = tid >> 6, lane = tid & 63;
    const int wr   = w >> 1,  wc   = w & 1;
    const int row0 = blockIdx.y * 128, col0 = blockIdx.x * 128;

    f32x4 acc[4][4];
#pragma unroll
    for (int m = 0; m < 4; ++m)
#pragma unroll
        for (int n = 0; n < 4; ++n) acc[m][n] = (f32x4){0.f, 0.f, 0.f, 0.f};

    const int lr4 = lane >> 2;
    const int scb = lane & 3;

    auto stage = [&](int t, int buf) {
#pragma unroll
        for (int i = 0; i < 2; ++i) {
            int lr = w * 32 + i * 16 + lr4;
            int cbs = scb ^ ((lr >> 1) & 3);
            const unsigned short* ga = A + (size_t)(row0 + lr) * K + t * 32 + cbs * 8;
            gload_lds16(ga, &As[buf][(w * 32 + i * 16) * 32]);
            const unsigned short* gb = Bt + (size_t)(col0 + lr) * K + t * 32 + cbs * 8;
            gload_lds16(gb, &Bs[buf][(w * 32 + i * 16) * 32]);
        }
    };

    const int nt = K / 32;
    stage(0, 0);
    int cur = 0;
    const int fr = lane & 15, fq = lane >> 4;
    for (int t = 0; t < nt; ++t) {
        __syncthreads();
        if (t + 1 < nt) stage(t + 1, cur ^ 1);
        bf16x8 af[4], bf[4];
#pragma unroll
        for (int m = 0; m < 4; ++m) {
            int ra = wr * 64 + m * 16 + fr;
            af[m] = *(const bf16x8*)&As[cur][ra * 32 + (fq ^ ((ra >> 1) & 3)) * 8];
            int rb = wc * 64 + m * 16 + fr;
            bf[m] = *(const bf16x8*)&Bs[cur][rb * 32 + (fq ^ ((rb >> 1) & 3)) * 8];
        }
#pragma unroll
        for (int m = 0; m < 4; ++m)
#pragma unroll
            for (int n = 0; n < 4; ++n)
                acc[m][n] = __builtin_amdgcn_mfma_f32_16x16x32_bf16(af[m], bf[n], acc[m][n], 0, 0, 0);
        cur ^= 1;
    }

#pragma unroll
    for (int m = 0; m < 4; ++m) {
#pragma unroll
        for (int n = 0; n < 4; ++n) {
            int col = col0 + wc * 64 + n * 16 + fr;
            float bv = BIAS ? bias[col] : 0.f;
#pragma unroll
            for (int j = 0; j < 4; ++j) {
                int row = row0 + wr * 64 + m * 16 + fq * 4 + j;
                size_t off = (size_t)row * N + col;
                float v = acc[m][n][j] + bv;
                if (RES) v += res[off];
                if (OUTB) ((unsigned short*)Cv)[off] = f2bf(v);
                else      ((float*)Cv)[off] = v;
            }
        }
    }
}

// ---------------- MFMA flash attention (causal), bf16 --------------------
// block: one (b,h), 64 q rows; 4 waves x 16 q rows. K and V^T tiles (64x64)
// double-buffered in LDS via global_load_lds with source-side XOR swizzle.
__global__ __launch_bounds__(256) void k_attn_mfma(
    const unsigned short* __restrict__ qkv, const unsigned short* __restrict__ vtg,
    unsigned short* __restrict__ attn)
{
    __shared__ __align__(16) unsigned short Ks[2][64*64];
    __shared__ __align__(16) unsigned short Vs[2][64*64];
    __shared__ __align__(16) unsigned short Ps[4][16*72];
    const int tid = threadIdx.x;
    const int w = tid >> 6, lane = tid & 63;
    const int fr = lane & 15, fq = lane >> 4;
    const int bh = blockIdx.x, b = bh / HH, h = bh % HH;
    const int qb = blockIdx.y * 64;
    const int nkt = qb / 64 + 1;
    const float scale = 0.03608439182435161f;  // 768^-0.5

    // Q A-frags in registers: row = w*16 + fr, k = ks*32 + fq*8 + e
    bf16x8 qf[2];
    {
        const unsigned short* qp = qkv + (size_t)(b*TT + qb + w*16 + fr)*(3*CC) + h*SS + fq*8;
        qf[0] = *(const bf16x8*)qp;
        qf[1] = *(const bf16x8*)(qp + 32);
    }

    auto stage = [&](int kt, int buf) {
        const unsigned short* kbase = qkv + (size_t)(b*TT + kt*64)*(3*CC) + CC + h*SS;
        const unsigned short* vbase = vtg + ((size_t)bh*64)*TT + kt*64;
#pragma unroll
        for (int p = 0; p < 2; ++p) {
            int s = p*256 + tid;
            int row = s >> 3;
            int blk = (s & 7) ^ (row & 7);      // source-side swizzle
            gload_lds16(kbase + (size_t)row*(3*CC) + blk*8, &Ks[buf][(p*256 + w*64)*8]);
            gload_lds16(vbase + (size_t)row*TT + blk*8,     &Vs[buf][(p*256 + w*64)*8]);
        }
    };

    float m[4] = {-INFINITY, -INFINITY, -INFINITY, -INFINITY};
    float l[4] = {0.f, 0.f, 0.f, 0.f};
    f32x4 oacc[4];
#pragma unroll
    for (int n = 0; n < 4; ++n) oacc[n] = (f32x4){0.f, 0.f, 0.f, 0.f};

    stage(0, 0);
    int cur = 0;
    for (int kt = 0; kt < nkt; ++kt) {
        __syncthreads();                        // drains prev-iter loads (vmcnt0)
        if (kt + 1 < nkt) stage(kt + 1, cur ^ 1);

        // ---- S = Q K^T (16q x 64k per wave) ----
        f32x4 sacc[4];
#pragma unroll
        for (int n = 0; n < 4; ++n) sacc[n] = (f32x4){0.f, 0.f, 0.f, 0.f};
#pragma unroll
        for (int ks = 0; ks < 2; ++ks) {
#pragma unroll
            for (int n = 0; n < 4; ++n) {
                int row = n*16 + fr;
                bf16x8 kf = *(const bf16x8*)&Ks[cur][row*64 + ((ks*4 + fq) ^ (row & 7))*8];
                sacc[n] = __builtin_amdgcn_mfma_f32_16x16x32_bf16(qf[ks], kf, sacc[n], 0, 0, 0);
            }
        }

        // ---- online softmax (rows q = fq*4+j, cols k = n*16+fr) ----
        float sv[4][4];   // [j][n]
        const bool lastt = (kt == nkt - 1);
        const int qloc = w*16 + fq*4;
#pragma unroll
        for (int n = 0; n < 4; ++n) {
            int kloc = n*16 + fr;
#pragma unroll
            for (int j = 0; j < 4; ++j) {
                float vv = sacc[n][j] * scale;
                if (lastt && kloc > qloc + j) vv = -INFINITY;
                sv[j][n] = vv;
            }
        }
        float mx[4], ls[4];
#pragma unroll
        for (int j = 0; j < 4; ++j)
            mx[j] = fmaxf(fmaxf(sv[j][0], sv[j][1]), fmaxf(sv[j][2], sv[j][3]));
#pragma unroll
        for (int d = 1; d < 16; d <<= 1)
#pragma unroll
            for (int j = 0; j < 4; ++j) mx[j] = fmaxf(mx[j], __shfl_xor(mx[j], d));
        float corr[4];
#pragma unroll
        for (int j = 0; j < 4; ++j) {
            float nm = fmaxf(m[j], mx[j]);
            corr[j] = __expf(m[j] - nm);
            m[j] = nm;
        }
#pragma unroll
        for (int j = 0; j < 4; ++j) {
            float s0 = 0.f;
#pragma unroll
            for (int n = 0; n < 4; ++n) {
                float p = __expf(sv[j][n] - m[j]);
                sv[j][n] = p;
                s0 += p;
            }
            ls[j] = s0;
        }
#pragma unroll
        for (int d = 1; d < 16; d <<= 1)
#pragma unroll
            for (int j = 0; j < 4; ++j) ls[j] += __shfl_xor(ls[j], d);
#pragma unroll
        for (int j = 0; j < 4; ++j) l[j] = l[j]*corr[j] + ls[j];
#pragma unroll
        for (int n = 0; n < 4; ++n)
#pragma unroll
            for (int j = 0; j < 4; ++j) oacc[n][j] *= corr[j];

        // ---- P -> LDS (bf16, [16 q][72-stride k]) ----
#pragma unroll
        for (int j = 0; j < 4; ++j)
#pragma unroll
            for (int n = 0; n < 4; ++n)
                Ps[w][(fq*4 + j)*72 + n*16 + fr] = f2bf(sv[j][n]);

        // ---- O += P V  (A-frag from Ps, B-frag from Vs) ----
#pragma unroll
        for (int ks = 0; ks < 2; ++ks) {
            bf16x8 pf = *(const bf16x8*)&Ps[w][fr*72 + ks*32 + fq*8];
#pragma unroll
            for (int n = 0; n < 4; ++n) {
                int row = n*16 + fr;
                bf16x8 vf = *(const bf16x8*)&Vs[cur][row*64 + ((ks*4 + fq) ^ (row & 7))*8];
                oacc[n] = __builtin_amdgcn_mfma_f32_16x16x32_bf16(pf, vf, oacc[n], 0, 0, 0);
            }
        }
        cur ^= 1;
    }

    // epilogue: O[q][d] / l
    float inv[4];
#pragma unroll
    for (int j = 0; j < 4; ++j) inv[j] = 1.0f / l[j];
#pragma unroll
    for (int n = 0; n < 4; ++n)
#pragma unroll
        for (int j = 0; j < 4; ++j) {
            size_t off = (size_t)(b*TT + qb + w*16 + fq*4 + j)*CC + h*SS + n*16 + fr;
            attn[off] = f2bf(oacc[n][j] * inv[j]);
        }
}

// ---------------- swiglu: sw = bf16(wx * vx * sigmoid(vx)) ----------------
__global__ void k_swiglu_b(const unsigned short* __restrict__ wx,
                           const unsigned short* __restrict__ vx,
                           unsigned short* __restrict__ sw, int n8) {
    int i = blockIdx.x * blockDim.x + threadIdx.x;
    if (i >= n8) return;
    uint4 wv = ((const uint4*)wx)[i];
    uint4 vv = ((const uint4*)vx)[i];
    uint4 r;
    float w0, w1, v0, v1;
    w0 = bfl(wv.x); w1 = bfh(wv.x); v0 = bfl(vv.x); v1 = bfh(vv.x);
    r.x = pk2(w0*v0/(1.f+__expf(-v0)), w1*v1/(1.f+__expf(-v1)));
    w0 = bfl(wv.y); w1 = bfh(wv.y); v0 = bfl(vv.y); v1 = bfh(vv.y);
    r.y = pk2(w0*v0/(1.f+__expf(-v0)), w1*v1/(1.f+__expf(-v1)));
    w0 = bfl(wv.z); w1 = bfh(wv.z); v0 = bfl(vv.z); v1 = bfh(vv.z);
    r.z = pk2(w0*v0/(1.f+__expf(-v0)), w1*v1/(1.f+__expf(-v1)));
    w0 = bfl(wv.w); w1 = bfh(wv.w); v0 = bfl(vv.w); v1 = bfh(vv.w);
    r.w = pk2(w0*v0/(1.f+__expf(-v0)), w1*v1/(1.f+__expf(-v1)));
    ((uint4*)sw)[i] = r;
}

// ---------------- launch ---------------------------------------------------
extern "C" void kernel_launch(void* const* d_in, const int* in_sizes, int n_in,
                              void* d_out, int out_size, void* d_ws, size_t ws_size,
                              hipStream_t stream)
{
    const float* x  = (const float*)d_in[0];
    const float* Wq = (const float*)d_in[1];
    const float* Wk = (const float*)d_in[2];
    const float* Wv = (const float*)d_in[3];
    const float* Wo = (const float*)d_in[4];
    const float* g1 = (const float*)d_in[5];
    const float* g2 = (const float*)d_in[6];
    const float* W1 = (const float*)d_in[7];
    const float* b1 = (const float*)d_in[8];
    const float* Ww = (const float*)d_in[9];
    const float* bw = (const float*)d_in[10];
    const float* Wg = (const float*)d_in[11];
    const float* bg = (const float*)d_in[12];
    const float* Wd = (const float*)d_in[13];
    const float* bd = (const float*)d_in[14];
    const float* W2 = (const float*)d_in[15];
    const float* b2 = (const float*)d_in[16];
    float* out = (float*)d_out;

    char* p = (char*)d_ws;
    auto alloc = [&](size_t bytes) { char* r = p; p += (bytes + 255) & ~(size_t)255; return r; };

    float*          scales = (float*)alloc(256);
    float*          part   = (float*)alloc(4096);
    float*          tab    = (float*)alloc((size_t)TT*32*2*4);
    unsigned short* hb     = (unsigned short*)alloc((size_t)NTOK*CC*2);
    unsigned short* wqkvT  = (unsigned short*)alloc((size_t)3*CC*CC*2);
    unsigned short* qkvb   = (unsigned short*)alloc((size_t)NTOK*3*CC*2);
    unsigned short* vtg    = (unsigned short*)alloc((size_t)BB*HH*SS*TT*2);
    unsigned short* attnb  = (unsigned short*)alloc((size_t)NTOK*CC*2);
    unsigned short* WoT    = (unsigned short*)alloc((size_t)CC*CC*2);
    unsigned short* W1T    = (unsigned short*)alloc((size_t)FFD*CC*2);
    unsigned short* ub     = (unsigned short*)alloc((size_t)NTOK*FFD*2);
    unsigned short* WwT    = (unsigned short*)alloc((size_t)HIDD*FFD*2);
    unsigned short* WgT    = (unsigned short*)alloc((size_t)HIDD*FFD*2);
    unsigned short* wxb    = (unsigned short*)alloc((size_t)NTOK*HIDD*2);
    unsigned short* vxb    = (unsigned short*)alloc((size_t)NTOK*HIDD*2);
    unsigned short* swb    = (unsigned short*)alloc((size_t)NTOK*HIDD*2);
    unsigned short* WdT    = (unsigned short*)alloc((size_t)FFD*HIDD*2);
    unsigned short* W2T    = (unsigned short*)alloc((size_t)CC*FFD*2);

    const int n = NTOK * CC;

    k_wqkvT<<<dim3(CC/32, SS/32, 36), 256, 0, stream>>>(Wq, Wk, Wv, wqkvT);
    k_wT<<<dim3(CC/32,  CC/32),  256, 0, stream>>>(Wo, WoT, CC,  CC);
    k_wT<<<dim3(CC/32,  FFD/32), 256, 0, stream>>>(W1, W1T, CC,  FFD);
    k_wT<<<dim3(FFD/32, HIDD/32),256, 0, stream>>>(Ww, WwT, FFD, HIDD);
    k_wT<<<dim3(FFD/32, HIDD/32),256, 0, stream>>>(Wg, WgT, FFD, HIDD);
    k_wT<<<dim3(HIDD/32,FFD/32), 256, 0, stream>>>(Wd, WdT, HIDD,FFD);
    k_wT<<<dim3(FFD/32, CC/32),  256, 0, stream>>>(W2, W2T, FFD, CC);
    k_rope_table<<<(TT*32)/256, 256, 0, stream>>>(tab);

    // rms1 -> h (bf16)
    k_sumsq_partial<<<1024, 256, 0, stream>>>(x, part, n/4);
    k_sumsq_final<<<1, 256, 0, stream>>>(part, scales + 0, 1024, 1.0f/(float)n);
    k_scale_gamma_b<<<(n/8)/256, 256, 0, stream>>>(x, g1, scales + 0, hb, n/8);

    // qkv = h @ WqkvT^T
    k_gemm_bf16<false,false,true><<<dim3(3*CC/128, NTOK/128), 256, 0, stream>>>(
        hb, wqkvT, nullptr, nullptr, qkvb, NTOK, 3*CC, CC);
    k_rope_apply_b<<<(NTOK*HH*32)/256, 256, 0, stream>>>(qkvb, tab);
    k_vT<<<dim3(BB*HH, TT/128), 256, 0, stream>>>(qkvb, vtg);

    // attention (MFMA)
    k_attn_mfma<<<dim3(BB*HH, TT/64), 256, 0, stream>>>(qkvb, vtg, attnb);

    // out1 = attn @ Wo + x
    k_gemm_bf16<false,true,false><<<dim3(CC/128, NTOK/128), 256, 0, stream>>>(
        attnb, WoT, nullptr, x, out, NTOK, CC, CC);

    // rms2 -> h2
    k_sumsq_partial<<<1024, 256, 0, stream>>>(out, part, n/4);
    k_sumsq_final<<<1, 256, 0, stream>>>(part, scales + 1, 1024, 1.0f/(float)n);
    k_scale_gamma_b<<<(n/8)/256, 256, 0, stream>>>(out, g2, scales + 1, hb, n/8);

    // FF
    k_gemm_bf16<true,false,true><<<dim3(FFD/128, NTOK/128), 256, 0, stream>>>(
        hb, W1T, b1, nullptr, ub, NTOK, FFD, CC);
    k_gemm_bf16<true,false,true><<<dim3(HIDD/128, NTOK/128), 256, 0, stream>>>(
        ub, WwT, bw, nullptr, wxb, NTOK, HIDD, FFD);
    k_gemm_bf16<true,false,true><<<dim3(HIDD/128, NTOK/128), 256, 0, stream>>>(
        ub, WgT, bg, nullptr, vxb, NTOK, HIDD, FFD);
    k_swiglu_b<<<(NTOK*HIDD/8)/256, 256, 0, stream>>>(wxb, vxb, swb, NTOK*HIDD/8);
    k_gemm_bf16<true,false,true><<<dim3(FFD/128, NTOK/128), 256, 0, stream>>>(
        swb, WdT, bd, nullptr, ub, NTOK, FFD, HIDD);
    k_gemm_bf16<true,true,false><<<dim3(CC/128, NTOK/128), 256, 0, stream>>>(
        ub, W2T, b2, out, out, NTOK, CC, FFD);
}